// Round 12
// baseline (133.863 us; speedup 1.0000x reference)
//
#include <hip/hip_runtime.h>

// VQ argmin via MFMA: x [16,64,64,64] NCHW fp32, codebook [1024,64] fp32.
// dist = ||e||^2 + (-2x).e ; -2x.e via exact bf16 3-way split GEMM (6 terms,
// dropped terms ~2^-26 < fp32 rounding noise; R8/R11 verified absmax 0).
//
// R12: single fused kernel (R11 lost ~55us to prep+second dispatch) and a
// barrier that drains NOTHING: B tiles are loaded to REGISTERS (f4/thread,
// issued before the current tile's MFMAs -> latency covered), split3'd, then
// ds_write'd to the LDS double buffer. At each __syncthreads the vmem queue
// is empty, so the compiler's vmcnt(0) drain is free — unlike R11's
// global_load_lds staging which exposed full L2 latency at every barrier.
// LDS tile image is byte-identical to R11's verified layout.

typedef float f4 __attribute__((ext_vector_type(4)));
typedef short s8v __attribute__((ext_vector_type(8)));
typedef unsigned int u32;

#define D_DIM 64
#define HW    4096
#define ROWS  128
#define INF_  __builtin_inff()
#define MFMA(a,b,c) __builtin_amdgcn_mfma_f32_16x16x32_bf16(a,b,c,0,0,0)

__device__ __forceinline__ unsigned short bf_rne(float f) {
    u32 u = __builtin_bit_cast(u32, f);
    u32 r = u + 0x7fffu + ((u >> 16) & 1u);
    return (unsigned short)(r >> 16);
}
__device__ __forceinline__ float bf_to_f(unsigned short h) {
    u32 u = ((u32)h) << 16;
    return __builtin_bit_cast(float, u);
}
__device__ __forceinline__ void split3(float f, unsigned short& h,
                                       unsigned short& m, unsigned short& l) {
    h = bf_rne(f);
    float f1 = f - bf_to_f(h);
    m = bf_rne(f1);
    float f2 = f1 - bf_to_f(m);
    l = bf_rne(f2);
}
__device__ __forceinline__ s8v pack8(unsigned short a0, unsigned short a1,
                                     unsigned short a2, unsigned short a3,
                                     unsigned short a4, unsigned short a5,
                                     unsigned short a6, unsigned short a7) {
    uint4 u;
    u.x = a0 | ((u32)a1 << 16);
    u.y = a2 | ((u32)a3 << 16);
    u.z = a4 | ((u32)a5 << 16);
    u.w = a6 | ((u32)a7 << 16);
    return __builtin_bit_cast(s8v, u);
}

// ---- macros ----
#define BUILD_AS(rs, s) {                                                    \
    const float* xr = (const float*)&xs4[wrow + (rs) * 16 + m_][0];          \
    f4 va = *(const f4*)(xr + (s) * 32 + ko);                                \
    f4 vb = *(const f4*)(xr + (s) * 32 + ko + 4);                            \
    unsigned short h0,h1,h2,h3,h4,h5,h6,h7;                                  \
    unsigned short q0,q1,q2,q3,q4,q5,q6,q7;                                  \
    unsigned short l0,l1,l2,l3,l4,l5,l6,l7;                                  \
    split3(-2.f * va.x, h0, q0, l0); split3(-2.f * va.y, h1, q1, l1);        \
    split3(-2.f * va.z, h2, q2, l2); split3(-2.f * va.w, h3, q3, l3);        \
    split3(-2.f * vb.x, h4, q4, l4); split3(-2.f * vb.y, h5, q5, l5);        \
    split3(-2.f * vb.z, h6, q6, l6); split3(-2.f * vb.w, h7, q7, l7);        \
    Ah##rs##s = pack8(h0,h1,h2,h3,h4,h5,h6,h7);                              \
    Am##rs##s = pack8(q0,q1,q2,q3,q4,q5,q6,q7);                              \
    Al##rs##s = pack8(l0,l1,l2,l3,l4,l5,l6,l7);                              \
}

// Split the 4 preloaded fp32 cb values (this thread's (code_l, ch=chq*4..+3)
// of tile T) and store to BUF in R11's exact chunk layout:
// chunk (s*3+L)*1024, lane' = g*16+code_l, bytes lane'*16 + (chq&1)*8.
#define SPLIT_WRITE(SRC, BUF) {                                              \
    unsigned short h0,h1,h2,h3, q0,q1,q2,q3, l0,l1,l2,l3;                    \
    split3((SRC).x, h0, q0, l0); split3((SRC).y, h1, q1, l1);                \
    split3((SRC).z, h2, q2, l2); split3((SRC).w, h3, q3, l3);                \
    char* dbase = (BUF) + sidx * 3072 + dlab;                                \
    uint2 wv;                                                                \
    wv.x = h0 | ((u32)h1 << 16); wv.y = h2 | ((u32)h3 << 16);                \
    *(uint2*)(dbase + 0)    = wv;                                            \
    wv.x = q0 | ((u32)q1 << 16); wv.y = q2 | ((u32)q3 << 16);                \
    *(uint2*)(dbase + 1024) = wv;                                            \
    wv.x = l0 | ((u32)l1 << 16); wv.y = l2 | ((u32)l3 << 16);                \
    *(uint2*)(dbase + 2048) = wv;                                            \
}

#define READ6(LP)                                                            \
    Bh0 = *(const s8v*)((LP) + 0);    Bm0 = *(const s8v*)((LP) + 1024);      \
    Bl0 = *(const s8v*)((LP) + 2048); Bh1 = *(const s8v*)((LP) + 3072);      \
    Bm1 = *(const s8v*)((LP) + 4096); Bl1 = *(const s8v*)((LP) + 5120);

#define MTERM(AH, AM, AL, BH, BM, BL, ACC)                                   \
    ACC = MFMA(AH, BH, ACC); ACC = MFMA(AH, BM, ACC);                        \
    ACC = MFMA(AM, BH, ACC); ACC = MFMA(AH, BL, ACC);                        \
    ACC = MFMA(AM, BM, ACC); ACC = MFMA(AL, BH, ACC);

#define COMPUTE24()                                                          \
    MTERM(Ah00, Am00, Al00, Bh0, Bm0, Bl0, a00)                              \
    MTERM(Ah10, Am10, Al10, Bh0, Bm0, Bl0, a10)                              \
    MTERM(Ah01, Am01, Al01, Bh1, Bm1, Bl1, a01)                              \
    MTERM(Ah11, Am11, Al11, Bh1, Bm1, Bl1, a11)

#define UPD(rs, i, SV) {                                                     \
    float v = SV[i] + en;                                                    \
    bool p = (v < best_##rs##_##i);                                          \
    best_##rs##_##i = p ? v : best_##rs##_##i;                               \
    idx_##rs##_##i  = p ? kn : idx_##rs##_##i;                               \
}
#define EPILOG(T) {                                                          \
    const int kn = (T) * 16 + m_;                                            \
    const float en = sEn[kn];                                                \
    f4 s0 = a00 + a01;                                                       \
    f4 s1 = a10 + a11;                                                       \
    UPD(0,0,s0) UPD(0,1,s0) UPD(0,2,s0) UPD(0,3,s0)                          \
    UPD(1,0,s1) UPD(1,1,s1) UPD(1,2,s1) UPD(1,3,s1)                          \
    a00 = (f4){0.f,0.f,0.f,0.f}; a01 = (f4){0.f,0.f,0.f,0.f};                \
    a10 = (f4){0.f,0.f,0.f,0.f}; a11 = (f4){0.f,0.f,0.f,0.f};                \
}

#define BFLY1(rs, i, msk) {                                                  \
    float ov = __shfl_xor(best_##rs##_##i, msk);                             \
    int   oi = __shfl_xor(idx_##rs##_##i,  msk);                             \
    bool p = (ov < best_##rs##_##i) ||                                       \
             (ov == best_##rs##_##i && oi < idx_##rs##_##i);                 \
    best_##rs##_##i = p ? ov : best_##rs##_##i;                              \
    idx_##rs##_##i  = p ? oi : idx_##rs##_##i;                               \
}
#define BFLY_ALL(msk)                                                        \
    BFLY1(0,0,msk) BFLY1(0,1,msk) BFLY1(0,2,msk) BFLY1(0,3,msk)              \
    BFLY1(1,0,msk) BFLY1(1,1,msk) BFLY1(1,2,msk) BFLY1(1,3,msk)

__global__ __launch_bounds__(256, 2) void vq_kernel(const float* __restrict__ x,
                                                    const float* __restrict__ cb,
                                                    int* __restrict__ out) {
    // LDSA: x tile 128 rows x 17 f4 (34816B) during prologue; after A-build
    // it is dead and the two 6144B B double-buffers alias its front.
    __shared__ __align__(16) char LDSA[34816];
    __shared__ float sEn[1024];

    const int tid = threadIdx.x;
    const int lane = tid & 63;
    const int quarter = __builtin_amdgcn_readfirstlane(tid >> 6);
    const int m_ = lane & 15;
    const int ko = (lane >> 4) * 8;
    const int lane16 = lane * 16;
    const int wrow = quarter * 32;           // this wave's row base in the tile
    const int n0 = blockIdx.x * ROWS;        // 128 | 4096 -> whole block same b
    const int b = n0 >> 12;
    const int hw0 = n0 & (HW - 1);

    // on-the-fly B split mapping: thread handles (code_l, ch = chq*4..+3)
    const int code_l = tid >> 4;             // 0..15 code within tile
    const int chq = tid & 15;                // 0..15 channel quad
    const int sidx = chq >> 3;               // kstep
    const int g = (chq >> 1) & 3;            // 8-ch group within kstep
    const int dlab = (g * 16 + code_l) * 16 + (chq & 1) * 8;  // byte in chunk

    f4 (*xs4)[17] = (f4(*)[17])(void*)LDSA;
    char* const buf0 = LDSA;
    char* const buf1 = LDSA + 6144;

    // ---- in-block e-norms: thread does codes tid, tid+256, ... (exact fp32,
    // same accumulation order as R8/R11's verified prep) ----
#pragma unroll
    for (int q = 0; q < 4; ++q) {
        const int k = q * 256 + tid;
        const f4* row = (const f4*)(cb + (size_t)k * 64);
        float sacc = 0.f;
#pragma unroll
        for (int i = 0; i < 16; ++i) {
            f4 v = row[i];
            sacc = fmaf(v.x, v.x, sacc);
            sacc = fmaf(v.y, v.y, sacc);
            sacc = fmaf(v.z, v.z, sacc);
            sacc = fmaf(v.w, v.w, sacc);
        }
        sEn[k] = sacc;
    }

    // ---- stage x tile: wave q loads channels q*16..q*16+15, rows lane/+64 ----
#pragma unroll
    for (int pass = 0; pass < 2; ++pass) {
        const int row = lane + pass * 64;
        const float* gp = x + ((size_t)b * D_DIM + quarter * 16) * HW + hw0 + row;
        float v[16];
#pragma unroll
        for (int i = 0; i < 16; ++i) v[i] = gp[(size_t)i * HW];
#pragma unroll
        for (int j = 0; j < 4; ++j)
            xs4[row][quarter * 4 + j] = (f4){v[4*j], v[4*j+1], v[4*j+2], v[4*j+3]};
    }
    __syncthreads();

    // A fragments of (-2x): 2 rowstripes x 2 ksteps x 3 levels (48 VGPRs)
    s8v Ah00, Am00, Al00, Ah01, Am01, Al01;
    s8v Ah10, Am10, Al10, Ah11, Am11, Al11;
    BUILD_AS(0,0) BUILD_AS(0,1) BUILD_AS(1,0) BUILD_AS(1,1)
    __syncthreads();   // xs4 dead; B buffers may overwrite the region

    f4 a00 = (f4){0.f,0.f,0.f,0.f}, a01 = (f4){0.f,0.f,0.f,0.f};
    f4 a10 = (f4){0.f,0.f,0.f,0.f}, a11 = (f4){0.f,0.f,0.f,0.f};
    float best_0_0=INF_, best_0_1=INF_, best_0_2=INF_, best_0_3=INF_;
    float best_1_0=INF_, best_1_1=INF_, best_1_2=INF_, best_1_3=INF_;
    int idx_0_0=0, idx_0_1=0, idx_0_2=0, idx_0_3=0;
    int idx_1_0=0, idx_1_1=0, idx_1_2=0, idx_1_3=0;

    s8v Bh0, Bm0, Bl0, Bh1, Bm1, Bl1;   // transient per-tile B frags

    const float* const bsrc = cb + (size_t)code_l * 64 + chq * 4;

    // prologue: split tile 0 into buf0
    {
        f4 bs = *(const f4*)bsrc;
        SPLIT_WRITE(bs, buf0)
    }
    __syncthreads();                     // tile 0 visible; vmem queue empty

#pragma unroll 1
    for (int tt = 0; tt < 32; ++tt) {
        const int t = 2 * tt;
        // tile t (in buf0): load src(t+1) FIRST (latency hidden by MFMAs)
        {
            f4 bs = *(const f4*)(bsrc + (size_t)(t + 1) * 1024);
            READ6(buf0 + lane16)
            COMPUTE24()
            EPILOG(t)
            SPLIT_WRITE(bs, buf1)        // waits its load here, post-MFMA
        }
        __syncthreads();                 // t+1 visible; no vmem outstanding
        // tile t+1 (in buf1): load src(t+2) unless done
        {
            const int tn = (tt != 31) ? (t + 2) : 0;   // uniform; discard on last
            f4 bs = *(const f4*)(bsrc + (size_t)tn * 1024);
            READ6(buf1 + lane16)
            COMPUTE24()
            EPILOG(t + 1)
            if (tt != 31) SPLIT_WRITE(bs, buf0)
        }
        __syncthreads();
    }

    // per-row argmin across the 16 code columns (16-lane groups)
    BFLY_ALL(1) BFLY_ALL(2) BFLY_ALL(4) BFLY_ALL(8)

    if (m_ == 0) {
        const int rbase = (lane >> 4) * 4;
        out[n0 + wrow + 0 * 16 + rbase + 0] = idx_0_0;
        out[n0 + wrow + 0 * 16 + rbase + 1] = idx_0_1;
        out[n0 + wrow + 0 * 16 + rbase + 2] = idx_0_2;
        out[n0 + wrow + 0 * 16 + rbase + 3] = idx_0_3;
        out[n0 + wrow + 1 * 16 + rbase + 0] = idx_1_0;
        out[n0 + wrow + 1 * 16 + rbase + 1] = idx_1_1;
        out[n0 + wrow + 1 * 16 + rbase + 2] = idx_1_2;
        out[n0 + wrow + 1 * 16 + rbase + 3] = idx_1_3;
    }
}

extern "C" void kernel_launch(void* const* d_in, const int* in_sizes, int n_in,
                              void* d_out, int out_size, void* d_ws, size_t ws_size,
                              hipStream_t stream) {
    const float* x  = (const float*)d_in[0];   // [16,64,64,64] fp32
    const float* cb = (const float*)d_in[1];   // [1024,64] fp32
    int*  out = (int*)d_out;                   // 65536 int32 indices

    vq_kernel<<<dim3(65536 / ROWS), dim3(256), 0, stream>>>(x, cb, out);
}

// Round 13
// 127.162 us; speedup vs baseline: 1.0527x; 1.0527x over previous
//
#include <hip/hip_runtime.h>

// VQ argmin via MFMA: x [16,64,64,64] NCHW fp32, codebook [1024,64] fp32.
// dist = ||e||^2 + (-2x).e ; -2x.e via exact bf16 3-way split GEMM (6 terms,
// dropped terms ~2^-26 < fp32 rounding noise; R8/R11/R12 verified absmax 0).
//
// R13 = R12 (fused, register-mediated B staging, clean barriers) with the
// split-write BANK FIX: R12's mapping put a wave's 64 uint2 stores on 8 banks
// (SQ_LDS_BANK_CONFLICT 1.1e7, MfmaUtil 23.5%). New mapping is slot-linear in
// lane (dlab = (tid&127)*8) — same chunk image, conflict-free stores. Plus
// depth-2 B prefetch so the barrier vmcnt(0) drain finds loads already landed.

typedef float f4 __attribute__((ext_vector_type(4)));
typedef short s8v __attribute__((ext_vector_type(8)));
typedef unsigned int u32;

#define D_DIM 64
#define HW    4096
#define ROWS  128
#define INF_  __builtin_inff()
#define MFMA(a,b,c) __builtin_amdgcn_mfma_f32_16x16x32_bf16(a,b,c,0,0,0)

__device__ __forceinline__ unsigned short bf_rne(float f) {
    u32 u = __builtin_bit_cast(u32, f);
    u32 r = u + 0x7fffu + ((u >> 16) & 1u);
    return (unsigned short)(r >> 16);
}
__device__ __forceinline__ float bf_to_f(unsigned short h) {
    u32 u = ((u32)h) << 16;
    return __builtin_bit_cast(float, u);
}
__device__ __forceinline__ void split3(float f, unsigned short& h,
                                       unsigned short& m, unsigned short& l) {
    h = bf_rne(f);
    float f1 = f - bf_to_f(h);
    m = bf_rne(f1);
    float f2 = f1 - bf_to_f(m);
    l = bf_rne(f2);
}
__device__ __forceinline__ s8v pack8(unsigned short a0, unsigned short a1,
                                     unsigned short a2, unsigned short a3,
                                     unsigned short a4, unsigned short a5,
                                     unsigned short a6, unsigned short a7) {
    uint4 u;
    u.x = a0 | ((u32)a1 << 16);
    u.y = a2 | ((u32)a3 << 16);
    u.z = a4 | ((u32)a5 << 16);
    u.w = a6 | ((u32)a7 << 16);
    return __builtin_bit_cast(s8v, u);
}

// ---- macros ----
#define BUILD_AS(rs, s) {                                                    \
    const float* xr = (const float*)&xs4[wrow + (rs) * 16 + m_][0];          \
    f4 va = *(const f4*)(xr + (s) * 32 + ko);                                \
    f4 vb = *(const f4*)(xr + (s) * 32 + ko + 4);                            \
    unsigned short h0,h1,h2,h3,h4,h5,h6,h7;                                  \
    unsigned short q0,q1,q2,q3,q4,q5,q6,q7;                                  \
    unsigned short l0,l1,l2,l3,l4,l5,l6,l7;                                  \
    split3(-2.f * va.x, h0, q0, l0); split3(-2.f * va.y, h1, q1, l1);        \
    split3(-2.f * va.z, h2, q2, l2); split3(-2.f * va.w, h3, q3, l3);        \
    split3(-2.f * vb.x, h4, q4, l4); split3(-2.f * vb.y, h5, q5, l5);        \
    split3(-2.f * vb.z, h6, q6, l6); split3(-2.f * vb.w, h7, q7, l7);        \
    Ah##rs##s = pack8(h0,h1,h2,h3,h4,h5,h6,h7);                              \
    Am##rs##s = pack8(q0,q1,q2,q3,q4,q5,q6,q7);                              \
    Al##rs##s = pack8(l0,l1,l2,l3,l4,l5,l6,l7);                              \
}

// Split this thread's 4 fp32 cb values (code_l, ch = chq*4..+3) of a tile and
// store to BUF in the verified R11 chunk image. dlab = slot*8 is lane-linear
// -> conflict-free 8B stores (R12's mapping was 8-way conflicted).
#define SPLIT_WRITE(SRC, BUF) {                                              \
    unsigned short h0,h1,h2,h3, q0,q1,q2,q3, l0,l1,l2,l3;                    \
    split3((SRC).x, h0, q0, l0); split3((SRC).y, h1, q1, l1);                \
    split3((SRC).z, h2, q2, l2); split3((SRC).w, h3, q3, l3);                \
    char* dbase = (BUF) + sidx * 3072 + dlab;                                \
    uint2 wv;                                                                \
    wv.x = h0 | ((u32)h1 << 16); wv.y = h2 | ((u32)h3 << 16);                \
    *(uint2*)(dbase + 0)    = wv;                                            \
    wv.x = q0 | ((u32)q1 << 16); wv.y = q2 | ((u32)q3 << 16);                \
    *(uint2*)(dbase + 1024) = wv;                                            \
    wv.x = l0 | ((u32)l1 << 16); wv.y = l2 | ((u32)l3 << 16);                \
    *(uint2*)(dbase + 2048) = wv;                                            \
}

#define READ6(LP)                                                            \
    Bh0 = *(const s8v*)((LP) + 0);    Bm0 = *(const s8v*)((LP) + 1024);      \
    Bl0 = *(const s8v*)((LP) + 2048); Bh1 = *(const s8v*)((LP) + 3072);      \
    Bm1 = *(const s8v*)((LP) + 4096); Bl1 = *(const s8v*)((LP) + 5120);

#define MTERM(AH, AM, AL, BH, BM, BL, ACC)                                   \
    ACC = MFMA(AH, BH, ACC); ACC = MFMA(AH, BM, ACC);                        \
    ACC = MFMA(AM, BH, ACC); ACC = MFMA(AH, BL, ACC);                        \
    ACC = MFMA(AM, BM, ACC); ACC = MFMA(AL, BH, ACC);

#define COMPUTE24()                                                          \
    MTERM(Ah00, Am00, Al00, Bh0, Bm0, Bl0, a00)                              \
    MTERM(Ah10, Am10, Al10, Bh0, Bm0, Bl0, a10)                              \
    MTERM(Ah01, Am01, Al01, Bh1, Bm1, Bl1, a01)                              \
    MTERM(Ah11, Am11, Al11, Bh1, Bm1, Bl1, a11)

#define UPD(rs, i, SV) {                                                     \
    float v = SV[i] + en;                                                    \
    bool p = (v < best_##rs##_##i);                                          \
    best_##rs##_##i = p ? v : best_##rs##_##i;                               \
    idx_##rs##_##i  = p ? kn : idx_##rs##_##i;                               \
}
#define EPILOG(T) {                                                          \
    const int kn = (T) * 16 + m_;                                            \
    const float en = sEn[kn];                                                \
    f4 s0 = a00 + a01;                                                       \
    f4 s1 = a10 + a11;                                                       \
    UPD(0,0,s0) UPD(0,1,s0) UPD(0,2,s0) UPD(0,3,s0)                          \
    UPD(1,0,s1) UPD(1,1,s1) UPD(1,2,s1) UPD(1,3,s1)                          \
    a00 = (f4){0.f,0.f,0.f,0.f}; a01 = (f4){0.f,0.f,0.f,0.f};                \
    a10 = (f4){0.f,0.f,0.f,0.f}; a11 = (f4){0.f,0.f,0.f,0.f};                \
}

#define BFLY1(rs, i, msk) {                                                  \
    float ov = __shfl_xor(best_##rs##_##i, msk);                             \
    int   oi = __shfl_xor(idx_##rs##_##i,  msk);                             \
    bool p = (ov < best_##rs##_##i) ||                                       \
             (ov == best_##rs##_##i && oi < idx_##rs##_##i);                 \
    best_##rs##_##i = p ? ov : best_##rs##_##i;                              \
    idx_##rs##_##i  = p ? oi : idx_##rs##_##i;                               \
}
#define BFLY_ALL(msk)                                                        \
    BFLY1(0,0,msk) BFLY1(0,1,msk) BFLY1(0,2,msk) BFLY1(0,3,msk)              \
    BFLY1(1,0,msk) BFLY1(1,1,msk) BFLY1(1,2,msk) BFLY1(1,3,msk)

__global__ __launch_bounds__(256, 2) void vq_kernel(const float* __restrict__ x,
                                                    const float* __restrict__ cb,
                                                    int* __restrict__ out) {
    // LDSA: x tile 128 rows x 17 f4 (34816B) during prologue; after A-build
    // it is dead and the two 6144B B double-buffers alias its front.
    __shared__ __align__(16) char LDSA[34816];
    __shared__ float sEn[1024];

    const int tid = threadIdx.x;
    const int lane = tid & 63;
    const int quarter = __builtin_amdgcn_readfirstlane(tid >> 6);
    const int m_ = lane & 15;
    const int ko = (lane >> 4) * 8;
    const int lane16 = lane * 16;
    const int wrow = quarter * 32;           // this wave's row base in the tile
    const int n0 = blockIdx.x * ROWS;        // 128 | 4096 -> whole block same b
    const int b = n0 >> 12;
    const int hw0 = n0 & (HW - 1);

    // B-split mapping, slot-linear in lane: thread t -> kstep sidx = t>>7,
    // 8B slot = t&127. Inverse of the chunk image: g = slot>>5,
    // code_l = (slot>>1)&15, p = slot&1, chq = sidx*8 + g*2 + p.
    const int sidx   = tid >> 7;
    const int slot   = tid & 127;
    const int code_l = (slot >> 1) & 15;
    const int g      = slot >> 5;
    const int p      = slot & 1;
    const int chq    = sidx * 8 + g * 2 + p;
    const int dlab   = slot * 8;

    f4 (*xs4)[17] = (f4(*)[17])(void*)LDSA;
    char* const buf0 = LDSA;
    char* const buf1 = LDSA + 6144;

    // ---- in-block e-norms: thread does codes tid, tid+256, ... (exact fp32,
    // same accumulation order as the verified prep) ----
#pragma unroll
    for (int q = 0; q < 4; ++q) {
        const int k = q * 256 + tid;
        const f4* row = (const f4*)(cb + (size_t)k * 64);
        float sacc = 0.f;
#pragma unroll
        for (int i = 0; i < 16; ++i) {
            f4 v = row[i];
            sacc = fmaf(v.x, v.x, sacc);
            sacc = fmaf(v.y, v.y, sacc);
            sacc = fmaf(v.z, v.z, sacc);
            sacc = fmaf(v.w, v.w, sacc);
        }
        sEn[k] = sacc;
    }

    // ---- stage x tile: wave q loads channels q*16..q*16+15, rows lane/+64 ----
#pragma unroll
    for (int pass = 0; pass < 2; ++pass) {
        const int row = lane + pass * 64;
        const float* gp = x + ((size_t)b * D_DIM + quarter * 16) * HW + hw0 + row;
        float v[16];
#pragma unroll
        for (int i = 0; i < 16; ++i) v[i] = gp[(size_t)i * HW];
#pragma unroll
        for (int j = 0; j < 4; ++j)
            xs4[row][quarter * 4 + j] = (f4){v[4*j], v[4*j+1], v[4*j+2], v[4*j+3]};
    }
    __syncthreads();

    // A fragments of (-2x): 2 rowstripes x 2 ksteps x 3 levels (48 VGPRs)
    s8v Ah00, Am00, Al00, Ah01, Am01, Al01;
    s8v Ah10, Am10, Al10, Ah11, Am11, Al11;
    BUILD_AS(0,0) BUILD_AS(0,1) BUILD_AS(1,0) BUILD_AS(1,1)
    __syncthreads();   // xs4 dead; B buffers may overwrite the region

    f4 a00 = (f4){0.f,0.f,0.f,0.f}, a01 = (f4){0.f,0.f,0.f,0.f};
    f4 a10 = (f4){0.f,0.f,0.f,0.f}, a11 = (f4){0.f,0.f,0.f,0.f};
    float best_0_0=INF_, best_0_1=INF_, best_0_2=INF_, best_0_3=INF_;
    float best_1_0=INF_, best_1_1=INF_, best_1_2=INF_, best_1_3=INF_;
    int idx_0_0=0, idx_0_1=0, idx_0_2=0, idx_0_3=0;
    int idx_1_0=0, idx_1_1=0, idx_1_2=0, idx_1_3=0;

    s8v Bh0, Bm0, Bl0, Bh1, Bm1, Bl1;   // transient per-tile B frags

    // per-thread B source (tile 0); tile t adds t*1024 floats
    const float* const bsrc = cb + (size_t)code_l * 64 + chq * 4;

    // prologue: split tile 0 -> buf0; prefetch tile 1 into registers
    f4 bs_a, bs_b;
    {
        f4 bs0 = *(const f4*)bsrc;
        SPLIT_WRITE(bs0, buf0)
        bs_a = *(const f4*)(bsrc + 1024);
    }
    __syncthreads();                     // tile 0 visible

#pragma unroll 1
    for (int tt = 0; tt < 32; ++tt) {
        const int t = 2 * tt;
        // half A: consume buf0 (tile t); prefetch t+2; write bs_a (t+1)->buf1
        {
            const int tn = (tt != 31) ? (t + 2) : 0;
            bs_b = *(const f4*)(bsrc + (size_t)tn * 1024);
            READ6(buf0 + lane16)
            COMPUTE24()
            EPILOG(t)
            SPLIT_WRITE(bs_a, buf1)
        }
        __syncthreads();                 // t+1 visible
        // half B: consume buf1 (tile t+1); prefetch t+3; write bs_b (t+2)->buf0
        {
            const int tn = (tt != 31) ? (t + 3) : 0;
            bs_a = *(const f4*)(bsrc + (size_t)tn * 1024);
            READ6(buf1 + lane16)
            COMPUTE24()
            EPILOG(t + 1)
            if (tt != 31) SPLIT_WRITE(bs_b, buf0)
        }
        __syncthreads();
    }

    // per-row argmin across the 16 code columns (16-lane groups)
    BFLY_ALL(1) BFLY_ALL(2) BFLY_ALL(4) BFLY_ALL(8)

    if (m_ == 0) {
        const int rbase = (lane >> 4) * 4;
        out[n0 + wrow + 0 * 16 + rbase + 0] = idx_0_0;
        out[n0 + wrow + 0 * 16 + rbase + 1] = idx_0_1;
        out[n0 + wrow + 0 * 16 + rbase + 2] = idx_0_2;
        out[n0 + wrow + 0 * 16 + rbase + 3] = idx_0_3;
        out[n0 + wrow + 1 * 16 + rbase + 0] = idx_1_0;
        out[n0 + wrow + 1 * 16 + rbase + 1] = idx_1_1;
        out[n0 + wrow + 1 * 16 + rbase + 2] = idx_1_2;
        out[n0 + wrow + 1 * 16 + rbase + 3] = idx_1_3;
    }
}

extern "C" void kernel_launch(void* const* d_in, const int* in_sizes, int n_in,
                              void* d_out, int out_size, void* d_ws, size_t ws_size,
                              hipStream_t stream) {
    const float* x  = (const float*)d_in[0];   // [16,64,64,64] fp32
    const float* cb = (const float*)d_in[1];   // [1024,64] fp32
    int*  out = (int*)d_out;                   // 65536 int32 indices

    vq_kernel<<<dim3(65536 / ROWS), dim3(256), 0, stream>>>(x, cb, out);
}